// Round 1
// baseline (81.836 us; speedup 1.0000x reference)
//
#include <hip/hip_runtime.h>

// LNCC loss: I,J [16,1,768,768] f32 -> out [16] f32
// out[b] = 1 - mean(cc) where cc = cross^2 / (Ivar*Jvar + EPS) over 9x9 box sums.

constexpr int BATCH = 16;
constexpr int H = 768;
constexpr int W = 768;
constexpr int R = 4;                      // win//2
constexpr float WS = 81.0f;               // win*win
constexpr float INV_WS = 1.0f / 81.0f;
constexpr float EPS = 3.0590232050182579e-07f;  // exp(-15)

constexpr int TH = 32;                    // output tile height
constexpr int TW = 64;                    // output tile width
constexpr int LW = TW + 2 * R;            // 72 staged cols
constexpr int LH = TH + 2 * R;            // 40 staged rows
constexpr int CW = LW + 1;                // 73: padded stride so phase-3 stride-4 reads hit all 32 banks
constexpr int NTHREADS = 512;

__global__ void zero_acc_kernel(float* acc) {
    if (threadIdx.x < BATCH) acc[threadIdx.x] = 0.0f;
}

__launch_bounds__(NTHREADS, 4)
__global__ void lncc_kernel(const float* __restrict__ gI, const float* __restrict__ gJ,
                            float* __restrict__ acc)
{
    __shared__ float sI[LH * LW];
    __shared__ float sJ[LH * LW];
    __shared__ float csI [TH * CW];
    __shared__ float csJ [TH * CW];
    __shared__ float csII[TH * CW];
    __shared__ float csJJ[TH * CW];
    __shared__ float csIJ[TH * CW];
    __shared__ float wsum[NTHREADS / 64];

    const int b   = blockIdx.z;
    const int x0  = blockIdx.x * TW;
    const int y0  = blockIdx.y * TH;
    const int tid = threadIdx.x;

    const float* __restrict__ Ib = gI + (size_t)b * (H * W);
    const float* __restrict__ Jb = gJ + (size_t)b * (H * W);

    // ---- Phase 1: stage (LH x LW) input tiles with zero padding ----
    for (int li = tid; li < LH * LW; li += NTHREADS) {
        const int r = li / LW;
        const int c = li - r * LW;
        const int gy = y0 - R + r;
        const int gx = x0 - R + c;
        float vi = 0.0f, vj = 0.0f;
        if (gy >= 0 && gy < H && gx >= 0 && gx < W) {
            const int gidx = gy * W + gx;
            vi = Ib[gidx];
            vj = Jb[gidx];
        }
        sI[li] = vi;
        sJ[li] = vj;
    }
    __syncthreads();

    // ---- Phase 2: vertical 9-row colsums of the 5 channels (4 rows/thread, sliding) ----
    for (int t = tid; t < (TH / 4) * LW; t += NTHREADS) {
        const int c  = t % LW;
        const int r4 = (t / LW) * 4;
        float bI[12], bJ[12];
        #pragma unroll
        for (int k = 0; k < 12; ++k) {
            bI[k] = sI[(r4 + k) * LW + c];
            bJ[k] = sJ[(r4 + k) * LW + c];
        }
        float aI = 0.0f, aJ = 0.0f, aII = 0.0f, aJJ = 0.0f, aIJ = 0.0f;
        #pragma unroll
        for (int k = 0; k < 9; ++k) {
            const float v = bI[k], w = bJ[k];
            aI += v; aJ += w;
            aII = fmaf(v, v, aII);
            aJJ = fmaf(w, w, aJJ);
            aIJ = fmaf(v, w, aIJ);
        }
        int o = r4 * CW + c;
        csI[o] = aI; csJ[o] = aJ; csII[o] = aII; csJJ[o] = aJJ; csIJ[o] = aIJ;
        #pragma unroll
        for (int s = 1; s < 4; ++s) {
            const float v  = bI[8 + s], w  = bJ[8 + s];
            const float ov = bI[s - 1], ow = bJ[s - 1];
            aI  += v - ov;
            aJ  += w - ow;
            aII += v * v - ov * ov;
            aJJ += w * w - ow * ow;
            aIJ += v * w - ov * ow;
            o += CW;
            csI[o] = aI; csJ[o] = aJ; csII[o] = aII; csJJ[o] = aJJ; csIJ[o] = aIJ;
        }
    }
    __syncthreads();

    // ---- Phase 3: horizontal 9-col sums (4 outputs/thread, sliding) + pixel math ----
    float accum = 0.0f;
    {
        const int t    = tid;              // exactly TH * (TW/4) = 512 tasks
        const int xg   = t % (TW / 4);
        const int r    = t / (TW / 4);
        const int base = r * CW + xg * 4;

        float hI[4], hJ[4], hII[4], hJJ[4], hIJ[4];

        auto hsum = [&](const float* __restrict__ cs, float out[4]) {
            float w0  = cs[base + 0],  w1  = cs[base + 1],  w2 = cs[base + 2];
            float w3  = cs[base + 3],  w4  = cs[base + 4],  w5 = cs[base + 5];
            float w6  = cs[base + 6],  w7  = cs[base + 7],  w8 = cs[base + 8];
            float w9  = cs[base + 9],  w10 = cs[base + 10], w11 = cs[base + 11];
            float s = w0 + w1 + w2 + w3 + w4 + w5 + w6 + w7 + w8;
            out[0] = s;
            s += w9  - w0; out[1] = s;
            s += w10 - w1; out[2] = s;
            s += w11 - w2; out[3] = s;
        };

        hsum(csI,  hI);
        hsum(csJ,  hJ);
        hsum(csII, hII);
        hsum(csJJ, hJJ);
        hsum(csIJ, hIJ);

        #pragma unroll
        for (int s = 0; s < 4; ++s) {
            const float Is = hI[s], Js = hJ[s];
            const float uI = Is * INV_WS;
            const float uJ = Js * INV_WS;
            float cross = hIJ[s] - (uJ * Is + uI * Js) + uI * uJ * WS;
            float Ivar  = hII[s] - 2.0f * uI * Is + uI * uI * WS;
            float Jvar  = hJJ[s] - 2.0f * uJ * Js + uJ * uJ * WS;
            float prod  = Ivar * Jvar;
            if (!(prod > EPS)) { cross = 1.0f; prod = 1.0f; }
            accum += cross * cross / (prod + EPS);
        }
    }

    // ---- Phase 4: block reduction + one atomic per block ----
    #pragma unroll
    for (int off = 32; off > 0; off >>= 1)
        accum += __shfl_down(accum, off, 64);
    const int wave = tid >> 6;
    if ((tid & 63) == 0) wsum[wave] = accum;
    __syncthreads();
    if (tid == 0) {
        float s = 0.0f;
        #pragma unroll
        for (int i = 0; i < NTHREADS / 64; ++i) s += wsum[i];
        atomicAdd(&acc[b], s);
    }
}

__global__ void finalize_kernel(const float* __restrict__ acc, float* __restrict__ out) {
    if (threadIdx.x < BATCH)
        out[threadIdx.x] = 1.0f - acc[threadIdx.x] * (1.0f / (float)(H * W));
}

extern "C" void kernel_launch(void* const* d_in, const int* in_sizes, int n_in,
                              void* d_out, int out_size, void* d_ws, size_t ws_size,
                              hipStream_t stream) {
    const float* I = (const float*)d_in[0];
    const float* J = (const float*)d_in[1];
    float* out = (float*)d_out;
    float* acc = (float*)d_ws;

    zero_acc_kernel<<<1, 64, 0, stream>>>(acc);

    dim3 grid(W / TW, H / TH, BATCH);   // 12 x 24 x 16 = 4608 blocks
    lncc_kernel<<<grid, NTHREADS, 0, stream>>>(I, J, acc);

    finalize_kernel<<<1, 64, 0, stream>>>(acc, out);
}